// Round 8
// baseline (2462.706 us; speedup 1.0000x reference)
//
#include <hip/hip_runtime.h>

typedef unsigned short u16;
typedef __attribute__((ext_vector_type(8))) short bf16x8;
typedef __attribute__((ext_vector_type(4))) float f32x4;

// ---- bf16 helpers (RNE) ----
__device__ inline float bf2f(u16 u) {
    unsigned v = ((unsigned)u) << 16;
    return __builtin_bit_cast(float, v);
}
__device__ inline u16 f2bf(float f) {
    unsigned u = __builtin_bit_cast(unsigned, f);
    u += 0x7fff + ((u >> 16) & 1);
    return (u16)(u >> 16);
}

// ============================================================
// Dtype detector (fp32 vs bf16 device buffers). flag=1 -> fp32.
// ============================================================
__global__ void detect_kernel(const u16* __restrict__ xr, int* __restrict__ flag) {
    __shared__ int red[4];
    const int t = threadIdx.x;
    int cnt = 0;
    for (int j = 0; j < 64; ++j) {
        u16 v = xr[(t * 64 + j) * 2];
        int e = (v >> 7) & 0xFF;
        cnt += (e >= 0x86);
    }
    for (int o = 32; o >= 1; o >>= 1) cnt += __shfl_xor(cnt, o);
    if ((t & 63) == 0) red[t >> 6] = cnt;
    __syncthreads();
    if (t == 0) flag[0] = ((red[0] + red[1] + red[2] + red[3]) > 1000) ? 1 : 0;
}

// ============================================================
// Weight transpose + convert-to-bf16: dst[C][R] = bf16(src[R][C])
// ============================================================
__global__ __launch_bounds__(256) void transpose_kernel(const float* __restrict__ srcf,
                                                        const u16* __restrict__ srch,
                                                        u16* __restrict__ dst,
                                                        int R, int C,
                                                        const int* __restrict__ flag) {
    __shared__ u16 tile[64][65];
    const bool isf32 = flag[0] != 0;
    const int t = threadIdx.x;
    const int c0 = blockIdx.x * 64, r0 = blockIdx.y * 64;
    const int lc = t & 63, lr4 = t >> 6;
#pragma unroll
    for (int i = 0; i < 16; ++i) {
        int row = i * 4 + lr4;
        size_t idx = (size_t)(r0 + row) * C + c0 + lc;
        tile[row][lc] = isf32 ? f2bf(srcf[idx]) : srch[idx];
    }
    __syncthreads();
#pragma unroll
    for (int i = 0; i < 16; ++i) {
        int drow = i * 4 + lr4;
        dst[(size_t)(c0 + drow) * R + r0 + lc] = tile[lc][drow];
    }
}

// ============================================================
// GEMM1: proj[65536][1024] = bf16(x)[65536][512] @ W1 + bias1, bf16 out
// ============================================================
__global__ __launch_bounds__(256) void gemm1_kernel(const float* __restrict__ xf,
                                                    const u16* __restrict__ xh,
                                                    const u16* __restrict__ w1t,
                                                    const float* __restrict__ b1f,
                                                    const u16* __restrict__ b1h,
                                                    u16* __restrict__ proj,
                                                    const int* __restrict__ flag) {
    __shared__ u16 Al[128 * 64];
    __shared__ u16 Bl[128 * 64];
    const bool isf32 = flag[0] != 0;
    const int t = threadIdx.x;
    const int lane = t & 63;
    const int w = t >> 6;
    const int r0 = blockIdx.y * 128;
    const int c0 = blockIdx.x * 128;
    const int wr = (w >> 1) * 64, wc = (w & 1) * 64;

    f32x4 acc[4][4] = {};

    for (int kt = 0; kt < 8; ++kt) {
        const int k0 = kt * 64;
#pragma unroll
        for (int i = 0; i < 4; ++i) {
            int c = i * 256 + t;
            int row = c >> 3;
            int off = (c & 7) * 8;
            size_t gidx = (size_t)(r0 + row) * 512 + k0 + off;
            bf16x8 av;
            if (isf32) {
                f32x4 f0 = *(const f32x4*)&xf[gidx];
                f32x4 f1 = *(const f32x4*)&xf[gidx + 4];
#pragma unroll
                for (int j = 0; j < 4; ++j) {
                    av[j] = (short)f2bf(f0[j]);
                    av[j + 4] = (short)f2bf(f1[j]);
                }
            } else {
                av = *(const bf16x8*)&xh[gidx];
            }
            *(bf16x8*)&Al[row * 64 + off] = av;
            *(bf16x8*)&Bl[row * 64 + off] =
                *(const bf16x8*)&w1t[(size_t)(c0 + row) * 512 + k0 + off];
        }
        __syncthreads();
#pragma unroll
        for (int kk = 0; kk < 64; kk += 32) {
            bf16x8 a[4], bb[4];
#pragma unroll
            for (int m = 0; m < 4; ++m)
                a[m] = *(const bf16x8*)&Al[(wr + m * 16 + (lane & 15)) * 64 + kk + (lane >> 4) * 8];
#pragma unroll
            for (int n = 0; n < 4; ++n)
                bb[n] = *(const bf16x8*)&Bl[(wc + n * 16 + (lane & 15)) * 64 + kk + (lane >> 4) * 8];
#pragma unroll
            for (int m = 0; m < 4; ++m)
#pragma unroll
                for (int n = 0; n < 4; ++n)
                    acc[m][n] = __builtin_amdgcn_mfma_f32_16x16x32_bf16(a[m], bb[n], acc[m][n], 0, 0, 0);
        }
        __syncthreads();
    }

#pragma unroll
    for (int n = 0; n < 4; ++n) {
        int col = c0 + wc + n * 16 + (lane & 15);
        float bv = isf32 ? b1f[col] : bf2f(b1h[col]);
#pragma unroll
        for (int m = 0; m < 4; ++m) {
            int rbase = r0 + wr + m * 16 + (lane >> 4) * 4;
#pragma unroll
            for (int i = 0; i < 4; ++i)
                proj[(size_t)(rbase + i) * 1024 + col] = f2bf(acc[m][n][i] + bv);
        }
    }
}

// ============================================================
// Fused attention per wg = (batch b, 16 query rows). 512 thr = 8 waves.
// LDS = exactly 32768 B -> 2+ wgs/CU co-resident (r4-proven structure).
// Grid = 4096 linear wgs, XCD-pinned: xcd=i&7, q=(i>>3)&63, b=(i>>9)*8+xcd
// (all 64 q-tiles of batch b on XCD b&7 -> K/V slab L2-resident, r6-proven).
// LDS: P bf16 [16][1024] XOR-swizzled; redm/reds [16][8] overlay first 1 KiB
// (consumed before P write); O overlays swizzled after PV.
// Wave w owns: QK m-cols [128w,128w+128) | PV e-cols [128w,128w+128) |
//              GEMM2 d-cols [64w,64w+64).
// ============================================================
__global__ __launch_bounds__(512) void attn_kernel(const u16* __restrict__ proj,
                                                   const u16* __restrict__ w2t,
                                                   const float* __restrict__ b2f,
                                                   const u16* __restrict__ b2h,
                                                   float* __restrict__ outf,
                                                   u16* __restrict__ outh,
                                                   const int* __restrict__ flag) {
    __shared__ u16 Pl[16 * 1024];           // 32768 B exactly
    const bool isf32 = flag[0] != 0;
    const int t = threadIdx.x;
    const int lane = t & 63;
    const int w = t >> 6;                   // 0..7
    const int i_wg = blockIdx.x;
    const int xcd = i_wg & 7;
    const int q = (i_wg >> 3) & 63;
    const int b = (i_wg >> 9) * 8 + xcd;
    const int n0 = q * 16;
    const u16* pb = proj + (size_t)b * 1024 * 1024;
    const int g = lane >> 4;
    const int lr = lane & 15;

    // ---- Phase 1: S = Q @ relu(K)^T / 32, in registers (8 cf frags)
    f32x4 acc[8] = {};
    const int mw = w * 128;
    for (int kk = 0; kk < 1024; kk += 32) {
        const int e = kk + g * 8;
        bf16x8 a = *(const bf16x8*)&pb[(size_t)(n0 + lr) * 1024 + e];
        bf16x8 kf[8];
#pragma unroll
        for (int cf = 0; cf < 8; ++cf) {
            bf16x8 v = *(const bf16x8*)&pb[(size_t)(mw + cf * 16 + lr) * 1024 + e];
            v &= ~(v >> 15);   // bf16 relu
            kf[cf] = v;
        }
#pragma unroll
        for (int cf = 0; cf < 8; ++cf)
            acc[cf] = __builtin_amdgcn_mfma_f32_16x16x32_bf16(a, kf[cf], acc[cf], 0, 0, 0);
    }
    {
        const float sc = 1.0f / 32.0f;
#pragma unroll
        for (int cf = 0; cf < 8; ++cf)
#pragma unroll
            for (int i = 0; i < 4; ++i) acc[cf][i] *= sc;
    }

    // ---- Phase 2: softmax. Row ri = g*4 + i, 16 lr lanes x 8 cf cols per wave.
    float* redm = (float*)Pl;          // [16][8] floats (512 B)
    float* reds = (float*)Pl + 128;    // [16][8] floats (512 B)
    {
#pragma unroll
        for (int i = 0; i < 4; ++i) {
            float m = acc[0][i];
#pragma unroll
            for (int cf = 1; cf < 8; ++cf) m = fmaxf(m, acc[cf][i]);
            for (int o = 8; o >= 1; o >>= 1) m = fmaxf(m, __shfl_xor(m, o));
            if (lr == 0) redm[(g * 4 + i) * 8 + w] = m;
        }
    }
    __syncthreads();
    {
#pragma unroll
        for (int i = 0; i < 4; ++i) {
            int ri = g * 4 + i;
            float m = redm[ri * 8 + 0];
#pragma unroll
            for (int w2 = 1; w2 < 8; ++w2) m = fmaxf(m, redm[ri * 8 + w2]);
            float s = 0.f;
#pragma unroll
            for (int cf = 0; cf < 8; ++cf) {
                acc[cf][i] = __expf(acc[cf][i] - m);
                s += acc[cf][i];
            }
            for (int o = 8; o >= 1; o >>= 1) s += __shfl_xor(s, o);
            if (lr == 0) reds[ri * 8 + w] = s;
        }
    }
    __syncthreads();
    float inv[4];
    {
#pragma unroll
        for (int i = 0; i < 4; ++i) {
            int ri = g * 4 + i;
            float s = reds[ri * 8 + 0];
#pragma unroll
            for (int w2 = 1; w2 < 8; ++w2) s += reds[ri * 8 + w2];
            inv[i] = 1.0f / s;
        }
    }
    __syncthreads();   // reduce arrays consumed -> safe to overwrite with P
    {
        char* Pb = (char*)Pl;
#pragma unroll
        for (int i = 0; i < 4; ++i) {
            int ri = g * 4 + i;
            int rx = (ri & 7) << 4;
            char* prow = Pb + ri * 2048;
#pragma unroll
            for (int cf = 0; cf < 8; ++cf) {
                int c = mw + cf * 16 + lr;
                *(u16*)(prow + ((2 * c) ^ rx)) = f2bf(acc[cf][i] * inv[i]);
            }
        }
    }
    __syncthreads();

    // ---- Phase 3: O = P @ V ; V gathered from proj (L2-resident via XCD pin)
    f32x4 acc2[8] = {};
    {
        const int ew = w * 128;
        const char* Pb = (const char*)Pl;
        const int rx = (lr & 7) << 4;
        for (int m0 = 0; m0 < 1024; m0 += 32) {
            const int mq = m0 + g * 8;
            bf16x8 pa = *(const bf16x8*)(Pb + lr * 2048 + ((2 * mq) ^ rx));
#pragma unroll
            for (int cf = 0; cf < 8; ++cf) {
                const u16* vp = &pb[(size_t)mq * 1024 + ew + cf * 16 + lr];
                bf16x8 vv;
#pragma unroll
                for (int j = 0; j < 8; ++j) vv[j] = (short)vp[(size_t)j * 1024];
                acc2[cf] = __builtin_amdgcn_mfma_f32_16x16x32_bf16(pa, vv, acc2[cf], 0, 0, 0);
            }
        }
    }
    __syncthreads();   // all P reads done -> overlay O (XOR-swizzled, stride 2048 B)
    {
        const int ew = w * 128;
        char* Ob = (char*)Pl;
#pragma unroll
        for (int cf = 0; cf < 8; ++cf)
#pragma unroll
            for (int i = 0; i < 4; ++i) {
                int orow = g * 4 + i;
                int rx = (orow & 7) << 4;
                *(u16*)(Ob + orow * 2048 + ((2 * (ew + cf * 16 + lr)) ^ rx)) =
                    f2bf(acc2[cf][i]);
            }
    }
    __syncthreads();

    // ---- Phase 4: out = relu(O @ W2 + bias2); wave owns 64 output cols
    {
        f32x4 acc3[4] = {};
        const int dw = w * 64;
        const char* Ob = (const char*)Pl;
        const int rx = (lr & 7) << 4;
        for (int kk = 0; kk < 1024; kk += 32) {
            const int e0 = kk + g * 8;
            bf16x8 oa = *(const bf16x8*)(Ob + lr * 2048 + ((2 * e0) ^ rx));
            bf16x8 wb[4];
#pragma unroll
            for (int cf = 0; cf < 4; ++cf)
                wb[cf] = *(const bf16x8*)&w2t[(size_t)(dw + cf * 16 + lr) * 1024 + e0];
#pragma unroll
            for (int cf = 0; cf < 4; ++cf)
                acc3[cf] = __builtin_amdgcn_mfma_f32_16x16x32_bf16(oa, wb[cf], acc3[cf], 0, 0, 0);
        }
#pragma unroll
        for (int cf = 0; cf < 4; ++cf) {
            int d = dw + cf * 16 + lr;
            float bv = isf32 ? b2f[d] : bf2f(b2h[d]);
#pragma unroll
            for (int i = 0; i < 4; ++i) {
                float v = fmaxf(acc3[cf][i] + bv, 0.f);
                size_t oi = ((size_t)b * 1024 + n0 + g * 4 + i) * 512 + d;
                if (isf32) outf[oi] = v;
                else outh[oi] = f2bf(v);
            }
        }
    }
}

// ============================================================
// Launch. ws: [0,1MB) W1T | [1MB,2MB) W2T | [2MB,130MB) proj | flag @130MB
// ============================================================
extern "C" void kernel_launch(void* const* d_in, const int* in_sizes, int n_in,
                              void* d_out, int out_size, void* d_ws, size_t ws_size,
                              hipStream_t stream) {
    char* ws = (char*)d_ws;
    u16* W1T  = (u16*)ws;
    u16* W2T  = (u16*)(ws + (1u << 20));
    u16* proj = (u16*)(ws + (2u << 20));
    int* flag = (int*)(ws + ((size_t)130 << 20));

    detect_kernel<<<1, 256, 0, stream>>>((const u16*)d_in[0], flag);

    transpose_kernel<<<dim3(16, 8, 1), 256, 0, stream>>>(
        (const float*)d_in[1], (const u16*)d_in[1], W1T, 512, 1024, flag);
    transpose_kernel<<<dim3(8, 16, 1), 256, 0, stream>>>(
        (const float*)d_in[3], (const u16*)d_in[3], W2T, 1024, 512, flag);

    gemm1_kernel<<<dim3(8, 512), 256, 0, stream>>>(
        (const float*)d_in[0], (const u16*)d_in[0], W1T,
        (const float*)d_in[2], (const u16*)d_in[2], proj, flag);

    // fused attention + output projection: 4096 XCD-pinned wgs (64 qtiles x 64 b)
    attn_kernel<<<dim3(4096), 512, 0, stream>>>(
        proj, W2T, (const float*)d_in[4], (const u16*)d_in[4],
        (float*)d_out, (u16*)d_out, flag);
}

// Round 9
// 1821.992 us; speedup vs baseline: 1.3517x; 1.3517x over previous
//
#include <hip/hip_runtime.h>

typedef unsigned short u16;
typedef __attribute__((ext_vector_type(8))) short bf16x8;
typedef __attribute__((ext_vector_type(4))) float f32x4;

// ---- bf16 helpers (RNE) ----
__device__ inline float bf2f(u16 u) {
    unsigned v = ((unsigned)u) << 16;
    return __builtin_bit_cast(float, v);
}
__device__ inline u16 f2bf(float f) {
    unsigned u = __builtin_bit_cast(unsigned, f);
    u += 0x7fff + ((u >> 16) & 1);
    return (u16)(u >> 16);
}

// ============================================================
// Dtype detector (fp32 vs bf16 device buffers). flag=1 -> fp32.
// ============================================================
__global__ void detect_kernel(const u16* __restrict__ xr, int* __restrict__ flag) {
    __shared__ int red[4];
    const int t = threadIdx.x;
    int cnt = 0;
    for (int j = 0; j < 64; ++j) {
        u16 v = xr[(t * 64 + j) * 2];
        int e = (v >> 7) & 0xFF;
        cnt += (e >= 0x86);
    }
    for (int o = 32; o >= 1; o >>= 1) cnt += __shfl_xor(cnt, o);
    if ((t & 63) == 0) red[t >> 6] = cnt;
    __syncthreads();
    if (t == 0) flag[0] = ((red[0] + red[1] + red[2] + red[3]) > 1000) ? 1 : 0;
}

// ============================================================
// Weight transpose + convert-to-bf16: dst[C][R] = bf16(src[R][C])
// ============================================================
__global__ __launch_bounds__(256) void transpose_kernel(const float* __restrict__ srcf,
                                                        const u16* __restrict__ srch,
                                                        u16* __restrict__ dst,
                                                        int R, int C,
                                                        const int* __restrict__ flag) {
    __shared__ u16 tile[64][65];
    const bool isf32 = flag[0] != 0;
    const int t = threadIdx.x;
    const int c0 = blockIdx.x * 64, r0 = blockIdx.y * 64;
    const int lc = t & 63, lr4 = t >> 6;
#pragma unroll
    for (int i = 0; i < 16; ++i) {
        int row = i * 4 + lr4;
        size_t idx = (size_t)(r0 + row) * C + c0 + lc;
        tile[row][lc] = isf32 ? f2bf(srcf[idx]) : srch[idx];
    }
    __syncthreads();
#pragma unroll
    for (int i = 0; i < 16; ++i) {
        int drow = i * 4 + lr4;
        dst[(size_t)(c0 + drow) * R + r0 + lc] = tile[lc][drow];
    }
}

// ============================================================
// bf16 transpose (per batch z): dst[b][C][R] = src[b][R][C], R=C=1024
// ============================================================
__global__ __launch_bounds__(256) void transpose_bf16_kernel(const u16* __restrict__ src,
                                                             u16* __restrict__ dst) {
    __shared__ u16 tile[64][65];
    const int t = threadIdx.x;
    const int c0 = blockIdx.x * 64, r0 = blockIdx.y * 64;
    const size_t boff = (size_t)blockIdx.z * 1024 * 1024;
    src += boff;
    dst += boff;
    const int lc = t & 63, lr4 = t >> 6;
#pragma unroll
    for (int i = 0; i < 16; ++i) {
        int row = i * 4 + lr4;
        tile[row][lc] = src[(size_t)(r0 + row) * 1024 + c0 + lc];
    }
    __syncthreads();
#pragma unroll
    for (int i = 0; i < 16; ++i) {
        int drow = i * 4 + lr4;
        dst[(size_t)(c0 + drow) * 1024 + r0 + lc] = tile[lc][drow];
    }
}

// ============================================================
// GEMM1: proj[65536][1024] = bf16(x)[65536][512] @ W1 + bias1, bf16 out
// ============================================================
__global__ __launch_bounds__(256) void gemm1_kernel(const float* __restrict__ xf,
                                                    const u16* __restrict__ xh,
                                                    const u16* __restrict__ w1t,
                                                    const float* __restrict__ b1f,
                                                    const u16* __restrict__ b1h,
                                                    u16* __restrict__ proj,
                                                    const int* __restrict__ flag) {
    __shared__ u16 Al[128 * 64];
    __shared__ u16 Bl[128 * 64];
    const bool isf32 = flag[0] != 0;
    const int t = threadIdx.x;
    const int lane = t & 63;
    const int w = t >> 6;
    const int r0 = blockIdx.y * 128;
    const int c0 = blockIdx.x * 128;
    const int wr = (w >> 1) * 64, wc = (w & 1) * 64;

    f32x4 acc[4][4] = {};

    for (int kt = 0; kt < 8; ++kt) {
        const int k0 = kt * 64;
#pragma unroll
        for (int i = 0; i < 4; ++i) {
            int c = i * 256 + t;
            int row = c >> 3;
            int off = (c & 7) * 8;
            size_t gidx = (size_t)(r0 + row) * 512 + k0 + off;
            bf16x8 av;
            if (isf32) {
                f32x4 f0 = *(const f32x4*)&xf[gidx];
                f32x4 f1 = *(const f32x4*)&xf[gidx + 4];
#pragma unroll
                for (int j = 0; j < 4; ++j) {
                    av[j] = (short)f2bf(f0[j]);
                    av[j + 4] = (short)f2bf(f1[j]);
                }
            } else {
                av = *(const bf16x8*)&xh[gidx];
            }
            *(bf16x8*)&Al[row * 64 + off] = av;
            *(bf16x8*)&Bl[row * 64 + off] =
                *(const bf16x8*)&w1t[(size_t)(c0 + row) * 512 + k0 + off];
        }
        __syncthreads();
#pragma unroll
        for (int kk = 0; kk < 64; kk += 32) {
            bf16x8 a[4], bb[4];
#pragma unroll
            for (int m = 0; m < 4; ++m)
                a[m] = *(const bf16x8*)&Al[(wr + m * 16 + (lane & 15)) * 64 + kk + (lane >> 4) * 8];
#pragma unroll
            for (int n = 0; n < 4; ++n)
                bb[n] = *(const bf16x8*)&Bl[(wc + n * 16 + (lane & 15)) * 64 + kk + (lane >> 4) * 8];
#pragma unroll
            for (int m = 0; m < 4; ++m)
#pragma unroll
                for (int n = 0; n < 4; ++n)
                    acc[m][n] = __builtin_amdgcn_mfma_f32_16x16x32_bf16(a[m], bb[n], acc[m][n], 0, 0, 0);
        }
        __syncthreads();
    }

#pragma unroll
    for (int n = 0; n < 4; ++n) {
        int col = c0 + wc + n * 16 + (lane & 15);
        float bv = isf32 ? b1f[col] : bf2f(b1h[col]);
#pragma unroll
        for (int m = 0; m < 4; ++m) {
            int rbase = r0 + wr + m * 16 + (lane >> 4) * 4;
#pragma unroll
            for (int i = 0; i < 4; ++i)
                proj[(size_t)(rbase + i) * 1024 + col] = f2bf(acc[m][n][i] + bv);
        }
    }
}

// ============================================================
// Fused attention per wg = (batch b, 32 query rows). 512 thr = 8 waves.
// r6-proven structure (replay-stable): QBLK=32, 64 KiB LDS, XCD-pinned grid
// (xcd=i&7, q=(i>>3)&31, b=(i>>8)*8+xcd -> batch slab L2-resident).
// PT=true: phase-3 V-fragments are 16B vector loads from projT (e-major);
// PT=false: r6 scalar-gather fallback.
// ============================================================
template <bool PT>
__global__ __launch_bounds__(512) void attn_kernel(const u16* __restrict__ proj,
                                                   const u16* __restrict__ projT,
                                                   const u16* __restrict__ w2t,
                                                   const float* __restrict__ b2f,
                                                   const u16* __restrict__ b2h,
                                                   float* __restrict__ outf,
                                                   u16* __restrict__ outh,
                                                   const int* __restrict__ flag) {
    __shared__ u16 Pl[32 * 1024];           // 65536 B exactly
    const bool isf32 = flag[0] != 0;
    const int t = threadIdx.x;
    const int lane = t & 63;
    const int w = t >> 6;
    const int i_wg = blockIdx.x;
    const int xcd = i_wg & 7;
    const int q = (i_wg >> 3) & 31;
    const int b = (i_wg >> 8) * 8 + xcd;
    const int n0 = q * 32;
    const u16* pb = proj + (size_t)b * 1024 * 1024;
    const int g = lane >> 4;
    const int lr = lane & 15;

    // ---- Phase 1: S = Q @ relu(K)^T / 32, in registers (2 rf x 8 cf frags)
    f32x4 acc[2][8] = {};
    const int mw = w * 128;
    for (int kk = 0; kk < 1024; kk += 32) {
        const int e = kk + g * 8;
        bf16x8 a[2];
#pragma unroll
        for (int rf = 0; rf < 2; ++rf)
            a[rf] = *(const bf16x8*)&pb[(size_t)(n0 + rf * 16 + lr) * 1024 + e];
        bf16x8 kf[8];
#pragma unroll
        for (int cf = 0; cf < 8; ++cf) {
            bf16x8 v = *(const bf16x8*)&pb[(size_t)(mw + cf * 16 + lr) * 1024 + e];
            v &= ~(v >> 15);   // bf16 relu
            kf[cf] = v;
        }
#pragma unroll
        for (int rf = 0; rf < 2; ++rf)
#pragma unroll
            for (int cf = 0; cf < 8; ++cf)
                acc[rf][cf] = __builtin_amdgcn_mfma_f32_16x16x32_bf16(a[rf], kf[cf], acc[rf][cf], 0, 0, 0);
    }
    {
        const float sc = 1.0f / 32.0f;
#pragma unroll
        for (int rf = 0; rf < 2; ++rf)
#pragma unroll
            for (int cf = 0; cf < 8; ++cf)
#pragma unroll
                for (int i = 0; i < 4; ++i) acc[rf][cf][i] *= sc;
    }

    // ---- Phase 2: softmax. Row ri = rf*16 + g*4 + i, cols across 16 lr x 8 cf.
    float* redm = (float*)Pl;          // [32][8] floats (1 KiB)
    float* reds = (float*)Pl + 256;    // [32][8] floats (1 KiB)
    {
#pragma unroll
        for (int rf = 0; rf < 2; ++rf)
#pragma unroll
            for (int i = 0; i < 4; ++i) {
                float m = acc[rf][0][i];
#pragma unroll
                for (int cf = 1; cf < 8; ++cf) m = fmaxf(m, acc[rf][cf][i]);
                for (int o = 8; o >= 1; o >>= 1) m = fmaxf(m, __shfl_xor(m, o));
                if (lr == 0) redm[(rf * 16 + g * 4 + i) * 8 + w] = m;
            }
    }
    __syncthreads();
    {
#pragma unroll
        for (int rf = 0; rf < 2; ++rf)
#pragma unroll
            for (int i = 0; i < 4; ++i) {
                int ri = rf * 16 + g * 4 + i;
                float m = redm[ri * 8 + 0];
#pragma unroll
                for (int w2 = 1; w2 < 8; ++w2) m = fmaxf(m, redm[ri * 8 + w2]);
                float s = 0.f;
#pragma unroll
                for (int cf = 0; cf < 8; ++cf) {
                    acc[rf][cf][i] = __expf(acc[rf][cf][i] - m);
                    s += acc[rf][cf][i];
                }
                for (int o = 8; o >= 1; o >>= 1) s += __shfl_xor(s, o);
                if (lr == 0) reds[ri * 8 + w] = s;
            }
    }
    __syncthreads();
    float inv[2][4];
    {
#pragma unroll
        for (int rf = 0; rf < 2; ++rf)
#pragma unroll
            for (int i = 0; i < 4; ++i) {
                int ri = rf * 16 + g * 4 + i;
                float s = reds[ri * 8 + 0];
#pragma unroll
                for (int w2 = 1; w2 < 8; ++w2) s += reds[ri * 8 + w2];
                inv[rf][i] = 1.0f / s;
            }
    }
    __syncthreads();   // reduce arrays consumed -> safe to overwrite with P
    {
        char* Pb = (char*)Pl;
#pragma unroll
        for (int rf = 0; rf < 2; ++rf)
#pragma unroll
            for (int i = 0; i < 4; ++i) {
                int ri = rf * 16 + g * 4 + i;
                int rx = (ri & 7) << 4;
                char* prow = Pb + ri * 2048;
#pragma unroll
                for (int cf = 0; cf < 8; ++cf) {
                    int c = mw + cf * 16 + lr;
                    *(u16*)(prow + ((2 * c) ^ rx)) = f2bf(acc[rf][cf][i] * inv[rf][i]);
                }
            }
    }
    __syncthreads();

    // ---- Phase 3: O = P @ V
    f32x4 acc2[2][8] = {};
    {
        const int ew = w * 128;
        const char* Pb = (const char*)Pl;
        if (PT) {
            const u16* ptb = projT + (size_t)b * 1024 * 1024;
            for (int m0 = 0; m0 < 1024; m0 += 32) {
                const int mq = m0 + g * 8;
                bf16x8 pa[2];
#pragma unroll
                for (int rf = 0; rf < 2; ++rf) {
                    int pr = rf * 16 + lr;
                    pa[rf] = *(const bf16x8*)(Pb + pr * 2048 + ((2 * mq) ^ ((pr & 7) << 4)));
                }
#pragma unroll
                for (int cf = 0; cf < 8; ++cf) {
                    bf16x8 vv = *(const bf16x8*)&ptb[(size_t)(ew + cf * 16 + lr) * 1024 + mq];
#pragma unroll
                    for (int rf = 0; rf < 2; ++rf)
                        acc2[rf][cf] = __builtin_amdgcn_mfma_f32_16x16x32_bf16(pa[rf], vv, acc2[rf][cf], 0, 0, 0);
                }
            }
        } else {
            for (int m0 = 0; m0 < 1024; m0 += 32) {
                const int mq = m0 + g * 8;
                bf16x8 pa[2];
#pragma unroll
                for (int rf = 0; rf < 2; ++rf) {
                    int pr = rf * 16 + lr;
                    pa[rf] = *(const bf16x8*)(Pb + pr * 2048 + ((2 * mq) ^ ((pr & 7) << 4)));
                }
#pragma unroll
                for (int cf = 0; cf < 8; ++cf) {
                    const u16* vp = &pb[(size_t)mq * 1024 + ew + cf * 16 + lr];
                    bf16x8 vv;
#pragma unroll
                    for (int j = 0; j < 8; ++j) vv[j] = (short)vp[(size_t)j * 1024];
#pragma unroll
                    for (int rf = 0; rf < 2; ++rf)
                        acc2[rf][cf] = __builtin_amdgcn_mfma_f32_16x16x32_bf16(pa[rf], vv, acc2[rf][cf], 0, 0, 0);
                }
            }
        }
    }
    __syncthreads();   // all P reads done -> overlay O (XOR-swizzled, stride 1024)
    {
        const int ew = w * 128;
        char* Ob = (char*)Pl;
#pragma unroll
        for (int rf = 0; rf < 2; ++rf)
#pragma unroll
            for (int cf = 0; cf < 8; ++cf)
#pragma unroll
                for (int i = 0; i < 4; ++i) {
                    int orow = rf * 16 + g * 4 + i;
                    int rx = (orow & 7) << 4;
                    *(u16*)(Ob + orow * 2048 + ((2 * (ew + cf * 16 + lr)) ^ rx)) =
                        f2bf(acc2[rf][cf][i]);
                }
    }
    __syncthreads();

    // ---- Phase 4: out = relu(O @ W2 + bias2); wave owns 64 output cols
    {
        f32x4 acc3[2][4] = {};
        const int dw = w * 64;
        const char* Ob = (const char*)Pl;
        for (int kk = 0; kk < 1024; kk += 32) {
            const int e0 = kk + g * 8;
            bf16x8 oa[2];
#pragma unroll
            for (int rf = 0; rf < 2; ++rf) {
                int orow = rf * 16 + lr;
                oa[rf] = *(const bf16x8*)(Ob + orow * 2048 + ((2 * e0) ^ ((orow & 7) << 4)));
            }
            bf16x8 wb[4];
#pragma unroll
            for (int cf = 0; cf < 4; ++cf)
                wb[cf] = *(const bf16x8*)&w2t[(size_t)(dw + cf * 16 + lr) * 1024 + e0];
#pragma unroll
            for (int rf = 0; rf < 2; ++rf)
#pragma unroll
                for (int cf = 0; cf < 4; ++cf)
                    acc3[rf][cf] = __builtin_amdgcn_mfma_f32_16x16x32_bf16(oa[rf], wb[cf], acc3[rf][cf], 0, 0, 0);
        }
#pragma unroll
        for (int cf = 0; cf < 4; ++cf) {
            int d = dw + cf * 16 + lr;
            float bv = isf32 ? b2f[d] : bf2f(b2h[d]);
#pragma unroll
            for (int rf = 0; rf < 2; ++rf)
#pragma unroll
                for (int i = 0; i < 4; ++i) {
                    float v = fmaxf(acc3[rf][cf][i] + bv, 0.f);
                    size_t oi = ((size_t)b * 1024 + n0 + rf * 16 + g * 4 + i) * 512 + d;
                    if (isf32) outf[oi] = v;
                    else outh[oi] = f2bf(v);
                }
        }
    }
}

// ============================================================
// Launch. ws: [0,1MB) W1T | [1MB,2MB) W2T | [2MB,130MB) proj | flag @130MB
//         | projT @130MB+4KB (gated on ws_size >= 258MB+8KB; r5 proved it fits)
// ============================================================
extern "C" void kernel_launch(void* const* d_in, const int* in_sizes, int n_in,
                              void* d_out, int out_size, void* d_ws, size_t ws_size,
                              hipStream_t stream) {
    char* ws = (char*)d_ws;
    u16* W1T   = (u16*)ws;
    u16* W2T   = (u16*)(ws + (1u << 20));
    u16* proj  = (u16*)(ws + (2u << 20));
    int* flag  = (int*)(ws + ((size_t)130 << 20));
    u16* projT = (u16*)(ws + ((size_t)130 << 20) + 4096);
    const bool use_pt = ws_size >= (((size_t)258 << 20) + 8192);

    detect_kernel<<<1, 256, 0, stream>>>((const u16*)d_in[0], flag);

    transpose_kernel<<<dim3(16, 8, 1), 256, 0, stream>>>(
        (const float*)d_in[1], (const u16*)d_in[1], W1T, 512, 1024, flag);
    transpose_kernel<<<dim3(8, 16, 1), 256, 0, stream>>>(
        (const float*)d_in[3], (const u16*)d_in[3], W2T, 1024, 512, flag);

    gemm1_kernel<<<dim3(8, 512), 256, 0, stream>>>(
        (const float*)d_in[0], (const u16*)d_in[0], W1T,
        (const float*)d_in[2], (const u16*)d_in[2], proj, flag);

    if (use_pt) {
        transpose_bf16_kernel<<<dim3(16, 16, 64), 256, 0, stream>>>(proj, projT);
        attn_kernel<true><<<dim3(2048), 512, 0, stream>>>(
            proj, projT, W2T, (const float*)d_in[4], (const u16*)d_in[4],
            (float*)d_out, (u16*)d_out, flag);
    } else {
        attn_kernel<false><<<dim3(2048), 512, 0, stream>>>(
            proj, projT, W2T, (const float*)d_in[4], (const u16*)d_in[4],
            (float*)d_out, (u16*)d_out, flag);
    }
}

// Round 10
// 1402.092 us; speedup vs baseline: 1.7565x; 1.2995x over previous
//
#include <hip/hip_runtime.h>

typedef unsigned short u16;
typedef __attribute__((ext_vector_type(8))) short bf16x8;
typedef __attribute__((ext_vector_type(4))) float f32x4;

// ---- bf16 helpers (RNE) ----
__device__ inline float bf2f(u16 u) {
    unsigned v = ((unsigned)u) << 16;
    return __builtin_bit_cast(float, v);
}
__device__ inline u16 f2bf(float f) {
    unsigned u = __builtin_bit_cast(unsigned, f);
    u += 0x7fff + ((u >> 16) & 1);
    return (u16)(u >> 16);
}

// ============================================================
// Dtype detector (fp32 vs bf16 device buffers). flag=1 -> fp32.
// ============================================================
__global__ void detect_kernel(const u16* __restrict__ xr, int* __restrict__ flag) {
    __shared__ int red[4];
    const int t = threadIdx.x;
    int cnt = 0;
    for (int j = 0; j < 64; ++j) {
        u16 v = xr[(t * 64 + j) * 2];
        int e = (v >> 7) & 0xFF;
        cnt += (e >= 0x86);
    }
    for (int o = 32; o >= 1; o >>= 1) cnt += __shfl_xor(cnt, o);
    if ((t & 63) == 0) red[t >> 6] = cnt;
    __syncthreads();
    if (t == 0) flag[0] = ((red[0] + red[1] + red[2] + red[3]) > 1000) ? 1 : 0;
}

// ============================================================
// Weight transpose + convert-to-bf16: dst[C][R] = bf16(src[R][C])
// ============================================================
__global__ __launch_bounds__(256) void transpose_kernel(const float* __restrict__ srcf,
                                                        const u16* __restrict__ srch,
                                                        u16* __restrict__ dst,
                                                        int R, int C,
                                                        const int* __restrict__ flag) {
    __shared__ u16 tile[64][65];
    const bool isf32 = flag[0] != 0;
    const int t = threadIdx.x;
    const int c0 = blockIdx.x * 64, r0 = blockIdx.y * 64;
    const int lc = t & 63, lr4 = t >> 6;
#pragma unroll
    for (int i = 0; i < 16; ++i) {
        int row = i * 4 + lr4;
        size_t idx = (size_t)(r0 + row) * C + c0 + lc;
        tile[row][lc] = isf32 ? f2bf(srcf[idx]) : srch[idx];
    }
    __syncthreads();
#pragma unroll
    for (int i = 0; i < 16; ++i) {
        int drow = i * 4 + lr4;
        dst[(size_t)(c0 + drow) * R + r0 + lc] = tile[lc][drow];
    }
}

// ============================================================
// GEMM1: proj[65536][1024] = bf16(x)[65536][512] @ W1 + bias1, bf16 out
// ============================================================
__global__ __launch_bounds__(256) void gemm1_kernel(const float* __restrict__ xf,
                                                    const u16* __restrict__ xh,
                                                    const u16* __restrict__ w1t,
                                                    const float* __restrict__ b1f,
                                                    const u16* __restrict__ b1h,
                                                    u16* __restrict__ proj,
                                                    const int* __restrict__ flag) {
    __shared__ u16 Al[128 * 64];
    __shared__ u16 Bl[128 * 64];
    const bool isf32 = flag[0] != 0;
    const int t = threadIdx.x;
    const int lane = t & 63;
    const int w = t >> 6;
    const int r0 = blockIdx.y * 128;
    const int c0 = blockIdx.x * 128;
    const int wr = (w >> 1) * 64, wc = (w & 1) * 64;

    f32x4 acc[4][4] = {};

    for (int kt = 0; kt < 8; ++kt) {
        const int k0 = kt * 64;
#pragma unroll
        for (int i = 0; i < 4; ++i) {
            int c = i * 256 + t;
            int row = c >> 3;
            int off = (c & 7) * 8;
            size_t gidx = (size_t)(r0 + row) * 512 + k0 + off;
            bf16x8 av;
            if (isf32) {
                f32x4 f0 = *(const f32x4*)&xf[gidx];
                f32x4 f1 = *(const f32x4*)&xf[gidx + 4];
#pragma unroll
                for (int j = 0; j < 4; ++j) {
                    av[j] = (short)f2bf(f0[j]);
                    av[j + 4] = (short)f2bf(f1[j]);
                }
            } else {
                av = *(const bf16x8*)&xh[gidx];
            }
            *(bf16x8*)&Al[row * 64 + off] = av;
            *(bf16x8*)&Bl[row * 64 + off] =
                *(const bf16x8*)&w1t[(size_t)(c0 + row) * 512 + k0 + off];
        }
        __syncthreads();
#pragma unroll
        for (int kk = 0; kk < 64; kk += 32) {
            bf16x8 a[4], bb[4];
#pragma unroll
            for (int m = 0; m < 4; ++m)
                a[m] = *(const bf16x8*)&Al[(wr + m * 16 + (lane & 15)) * 64 + kk + (lane >> 4) * 8];
#pragma unroll
            for (int n = 0; n < 4; ++n)
                bb[n] = *(const bf16x8*)&Bl[(wc + n * 16 + (lane & 15)) * 64 + kk + (lane >> 4) * 8];
#pragma unroll
            for (int m = 0; m < 4; ++m)
#pragma unroll
                for (int n = 0; n < 4; ++n)
                    acc[m][n] = __builtin_amdgcn_mfma_f32_16x16x32_bf16(a[m], bb[n], acc[m][n], 0, 0, 0);
        }
        __syncthreads();
    }

#pragma unroll
    for (int n = 0; n < 4; ++n) {
        int col = c0 + wc + n * 16 + (lane & 15);
        float bv = isf32 ? b1f[col] : bf2f(b1h[col]);
#pragma unroll
        for (int m = 0; m < 4; ++m) {
            int rbase = r0 + wr + m * 16 + (lane >> 4) * 4;
#pragma unroll
            for (int i = 0; i < 4; ++i)
                proj[(size_t)(rbase + i) * 1024 + col] = f2bf(acc[m][n][i] + bv);
        }
    }
}

// ============================================================
// Attention core (phases 1-3 only) per wg = (batch b, 32 query rows).
// 512 thr = 8 waves; LDS = exactly 32768 B -> 2 wg/CU (r8-proven ~47% occ).
// XCD-pinned grid (r6-proven): xcd=i&7, q=(i>>3)&31, b=(i>>8)*8+xcd.
//  P1: S = Q @ relu(K)^T / 32 in registers (full 1024-key width)
//  P2: softmax in registers (cross-wave reduce via 2 KiB LDS overlay)
//  P3: PV in TWO 512-key passes; each pass stages P-half [32][512] bf16
//      (XOR-swizzled, 32 KiB) written by the 4 owning waves; V scalar-gather
//      from proj (beat projT in r6-vs-r9); acc2 accumulates across passes.
//  O written to global obuf (GEMM2 is a separate kernel).
// ============================================================
__global__ __launch_bounds__(512) void attn_kernel(const u16* __restrict__ proj,
                                                   u16* __restrict__ obuf) {
    __shared__ u16 Pl[32 * 512];            // 32768 B exactly
    const int t = threadIdx.x;
    const int lane = t & 63;
    const int w = t >> 6;                   // 0..7
    const int i_wg = blockIdx.x;
    const int xcd = i_wg & 7;
    const int q = (i_wg >> 3) & 31;
    const int b = (i_wg >> 8) * 8 + xcd;
    const int n0 = q * 32;
    const u16* pb = proj + (size_t)b * 1024 * 1024;
    const int g = lane >> 4;
    const int lr = lane & 15;

    // ---- Phase 1: S = Q @ relu(K)^T / 32, in registers (2 rf x 8 cf frags)
    f32x4 acc[2][8] = {};
    const int mw = w * 128;
#pragma unroll 2
    for (int kk = 0; kk < 1024; kk += 32) {
        const int e = kk + g * 8;
        bf16x8 a[2];
#pragma unroll
        for (int rf = 0; rf < 2; ++rf)
            a[rf] = *(const bf16x8*)&pb[(size_t)(n0 + rf * 16 + lr) * 1024 + e];
        bf16x8 kf[8];
#pragma unroll
        for (int cf = 0; cf < 8; ++cf) {
            bf16x8 v = *(const bf16x8*)&pb[(size_t)(mw + cf * 16 + lr) * 1024 + e];
            v &= ~(v >> 15);   // bf16 relu
            kf[cf] = v;
        }
#pragma unroll
        for (int rf = 0; rf < 2; ++rf)
#pragma unroll
            for (int cf = 0; cf < 8; ++cf)
                acc[rf][cf] = __builtin_amdgcn_mfma_f32_16x16x32_bf16(a[rf], kf[cf], acc[rf][cf], 0, 0, 0);
    }
    {
        const float sc = 1.0f / 32.0f;
#pragma unroll
        for (int rf = 0; rf < 2; ++rf)
#pragma unroll
            for (int cf = 0; cf < 8; ++cf)
#pragma unroll
                for (int i = 0; i < 4; ++i) acc[rf][cf][i] *= sc;
    }

    // ---- Phase 2: softmax. Row ri = rf*16 + g*4 + i, cols across 16 lr x 8 cf.
    float* redm = (float*)Pl;          // [32][8] floats (1 KiB) - overlay
    float* reds = (float*)Pl + 256;    // [32][8] floats (1 KiB) - overlay
    {
#pragma unroll
        for (int rf = 0; rf < 2; ++rf)
#pragma unroll
            for (int i = 0; i < 4; ++i) {
                float m = acc[rf][0][i];
#pragma unroll
                for (int cf = 1; cf < 8; ++cf) m = fmaxf(m, acc[rf][cf][i]);
                for (int o = 8; o >= 1; o >>= 1) m = fmaxf(m, __shfl_xor(m, o));
                if (lr == 0) redm[(rf * 16 + g * 4 + i) * 8 + w] = m;
            }
    }
    __syncthreads();
    {
#pragma unroll
        for (int rf = 0; rf < 2; ++rf)
#pragma unroll
            for (int i = 0; i < 4; ++i) {
                int ri = rf * 16 + g * 4 + i;
                float m = redm[ri * 8 + 0];
#pragma unroll
                for (int w2 = 1; w2 < 8; ++w2) m = fmaxf(m, redm[ri * 8 + w2]);
                float s = 0.f;
#pragma unroll
                for (int cf = 0; cf < 8; ++cf) {
                    acc[rf][cf][i] = __expf(acc[rf][cf][i] - m);
                    s += acc[rf][cf][i];
                }
                for (int o = 8; o >= 1; o >>= 1) s += __shfl_xor(s, o);
                if (lr == 0) reds[ri * 8 + w] = s;
            }
    }
    __syncthreads();
    float inv[2][4];
    {
#pragma unroll
        for (int rf = 0; rf < 2; ++rf)
#pragma unroll
            for (int i = 0; i < 4; ++i) {
                int ri = rf * 16 + g * 4 + i;
                float s = reds[ri * 8 + 0];
#pragma unroll
                for (int w2 = 1; w2 < 8; ++w2) s += reds[ri * 8 + w2];
                inv[rf][i] = 1.0f / s;
            }
    }
    __syncthreads();   // reduce arrays consumed -> P half may overwrite them

    // ---- Phase 3: O = P @ V in two 512-key passes; acc2 accumulates across.
    f32x4 acc2[2][8] = {};
    const int ew = w * 128;
#pragma unroll
    for (int h = 0; h < 2; ++h) {
        // write this half's P columns: waves 4h..4h+3 own key-cols [512h,512h+512)
        if ((w >> 2) == h) {
            char* Pb = (char*)Pl;
            const int mloc = (w & 3) * 128;   // local col base within the half
#pragma unroll
            for (int rf = 0; rf < 2; ++rf)
#pragma unroll
                for (int i = 0; i < 4; ++i) {
                    int ri = rf * 16 + g * 4 + i;
                    int rx = (ri & 7) << 4;
                    char* prow = Pb + ri * 1024;
#pragma unroll
                    for (int cf = 0; cf < 8; ++cf) {
                        int c = mloc + cf * 16 + lr;
                        *(u16*)(prow + ((2 * c) ^ rx)) = f2bf(acc[rf][cf][i] * inv[rf][i]);
                    }
                }
        }
        __syncthreads();
        // PV over keys [512h, 512h+512)
        const char* Pb = (const char*)Pl;
        for (int m0 = 0; m0 < 512; m0 += 32) {
            const int mloc = m0 + g * 8;
            const int mq = mloc + h * 512;
            bf16x8 pa[2];
#pragma unroll
            for (int rf = 0; rf < 2; ++rf) {
                int pr = rf * 16 + lr;
                pa[rf] = *(const bf16x8*)(Pb + pr * 1024 + ((2 * mloc) ^ ((pr & 7) << 4)));
            }
#pragma unroll
            for (int cf = 0; cf < 8; ++cf) {
                const u16* vp = &pb[(size_t)mq * 1024 + ew + cf * 16 + lr];
                bf16x8 vv;
#pragma unroll
                for (int j = 0; j < 8; ++j) vv[j] = (short)vp[(size_t)j * 1024];
#pragma unroll
                for (int rf = 0; rf < 2; ++rf)
                    acc2[rf][cf] = __builtin_amdgcn_mfma_f32_16x16x32_bf16(pa[rf], vv, acc2[rf][cf], 0, 0, 0);
            }
        }
        __syncthreads();
    }

    // ---- O -> global obuf [65536][1024] bf16 (row-major in e)
    {
#pragma unroll
        for (int rf = 0; rf < 2; ++rf)
#pragma unroll
            for (int cf = 0; cf < 8; ++cf)
#pragma unroll
                for (int i = 0; i < 4; ++i)
                    obuf[((size_t)b * 1024 + n0 + rf * 16 + g * 4 + i) * 1024 +
                         ew + cf * 16 + lr] = f2bf(acc2[rf][cf][i]);
    }
}

// ============================================================
// GEMM2: out[65536][512] = relu(O[65536][1024] @ W2 + bias2)
// gemm1 clone: 128x128 tile, BK=64, A=obuf bf16 row-major, B=W2T[512][1024].
// ============================================================
__global__ __launch_bounds__(256) void gemm2_kernel(const u16* __restrict__ obuf,
                                                    const u16* __restrict__ w2t,
                                                    const float* __restrict__ b2f,
                                                    const u16* __restrict__ b2h,
                                                    float* __restrict__ outf,
                                                    u16* __restrict__ outh,
                                                    const int* __restrict__ flag) {
    __shared__ u16 Al[128 * 64];
    __shared__ u16 Bl[128 * 64];
    const bool isf32 = flag[0] != 0;
    const int t = threadIdx.x;
    const int lane = t & 63;
    const int w = t >> 6;
    const int r0 = blockIdx.y * 128;
    const int c0 = blockIdx.x * 128;
    const int wr = (w >> 1) * 64, wc = (w & 1) * 64;

    f32x4 acc[4][4] = {};

    for (int kt = 0; kt < 16; ++kt) {
        const int k0 = kt * 64;
#pragma unroll
        for (int i = 0; i < 4; ++i) {
            int c = i * 256 + t;
            int row = c >> 3;
            int off = (c & 7) * 8;
            *(bf16x8*)&Al[row * 64 + off] =
                *(const bf16x8*)&obuf[(size_t)(r0 + row) * 1024 + k0 + off];
            *(bf16x8*)&Bl[row * 64 + off] =
                *(const bf16x8*)&w2t[(size_t)(c0 + row) * 1024 + k0 + off];
        }
        __syncthreads();
#pragma unroll
        for (int kk = 0; kk < 64; kk += 32) {
            bf16x8 a[4], bb[4];
#pragma unroll
            for (int m = 0; m < 4; ++m)
                a[m] = *(const bf16x8*)&Al[(wr + m * 16 + (lane & 15)) * 64 + kk + (lane >> 4) * 8];
#pragma unroll
            for (int n = 0; n < 4; ++n)
                bb[n] = *(const bf16x8*)&Bl[(wc + n * 16 + (lane & 15)) * 64 + kk + (lane >> 4) * 8];
#pragma unroll
            for (int m = 0; m < 4; ++m)
#pragma unroll
                for (int n = 0; n < 4; ++n)
                    acc[m][n] = __builtin_amdgcn_mfma_f32_16x16x32_bf16(a[m], bb[n], acc[m][n], 0, 0, 0);
        }
        __syncthreads();
    }

#pragma unroll
    for (int n = 0; n < 4; ++n) {
        int col = c0 + wc + n * 16 + (lane & 15);
        float bv = isf32 ? b2f[col] : bf2f(b2h[col]);
#pragma unroll
        for (int m = 0; m < 4; ++m) {
            int rbase = r0 + wr + m * 16 + (lane >> 4) * 4;
#pragma unroll
            for (int i = 0; i < 4; ++i) {
                float v = fmaxf(acc[m][n][i] + bv, 0.f);
                size_t oi = (size_t)(rbase + i) * 512 + col;
                if (isf32) outf[oi] = v;
                else outh[oi] = f2bf(v);
            }
        }
    }
}

// ============================================================
// Launch. ws: [0,1MB) W1T | [1MB,2MB) W2T | [2MB,130MB) proj | flag @130MB
//         | obuf [65536][1024] bf16 @130MB+4KB (258MB+4KB total, within
//         the ws bound proven by r5/r9's projT runs)
// ============================================================
extern "C" void kernel_launch(void* const* d_in, const int* in_sizes, int n_in,
                              void* d_out, int out_size, void* d_ws, size_t ws_size,
                              hipStream_t stream) {
    char* ws = (char*)d_ws;
    u16* W1T  = (u16*)ws;
    u16* W2T  = (u16*)(ws + (1u << 20));
    u16* proj = (u16*)(ws + (2u << 20));
    int* flag = (int*)(ws + ((size_t)130 << 20));
    u16* obuf = (u16*)(ws + ((size_t)130 << 20) + 4096);

    detect_kernel<<<1, 256, 0, stream>>>((const u16*)d_in[0], flag);

    transpose_kernel<<<dim3(16, 8, 1), 256, 0, stream>>>(
        (const float*)d_in[1], (const u16*)d_in[1], W1T, 512, 1024, flag);
    transpose_kernel<<<dim3(8, 16, 1), 256, 0, stream>>>(
        (const float*)d_in[3], (const u16*)d_in[3], W2T, 1024, 512, flag);

    gemm1_kernel<<<dim3(8, 512), 256, 0, stream>>>(
        (const float*)d_in[0], (const u16*)d_in[0], W1T,
        (const float*)d_in[2], (const u16*)d_in[2], proj, flag);

    // attention core: 2048 XCD-pinned wgs (32 qtiles x 64 batches)
    attn_kernel<<<dim3(2048), 512, 0, stream>>>(proj, obuf);

    // output projection: standard 128^2-tile GEMM
    gemm2_kernel<<<dim3(4, 512), 256, 0, stream>>>(
        obuf, W2T, (const float*)d_in[4], (const u16*)d_in[4],
        (float*)d_out, (u16*)d_out, flag);
}